// Round 13
// baseline (1340.381 us; speedup 1.0000x reference)
//
#include <hip/hip_runtime.h>
#include <math.h>

#define HH  64
#define TT  2048
#define IND 7
#define NT  768          // 256 L0 threads + 512 L1 threads

typedef _Float16 half_t;
typedef _Float16 h2v __attribute__((ext_vector_type(2)));
typedef _Float16 h8v __attribute__((ext_vector_type(8)));
typedef unsigned int u2v __attribute__((ext_vector_type(2)));

#define LOG2E 1.44269504088896f

// constant-index h2v slice of an h8v: exact VGPR subregister
#define S2C(V, I) __builtin_shufflevector(V, V, 2*(I), 2*(I)+1)

// f16 dot2 with fp32 accumulate
__device__ __forceinline__ float fdot2(h2v a, h2v b, float c) {
#if __has_builtin(__builtin_amdgcn_fdot2)
    return __builtin_amdgcn_fdot2(a, b, c, false);
#else
    return fmaf((float)a.x, (float)b.x, fmaf((float)a.y, (float)b.y, c));
#endif
}

__device__ __forceinline__ float exp2_fast(float x) {
#if __has_builtin(__builtin_amdgcn_exp2f)
    return __builtin_amdgcn_exp2f(x);
#else
    return exp2f(x);
#endif
}

// value held by the lane^32 partner (VALU pipe, v_permlane32_swap)
__device__ __forceinline__ float partner32(float x, int hi) {
#if __has_builtin(__builtin_amdgcn_permlane32_swap)
    u2v r = __builtin_amdgcn_permlane32_swap(__float_as_uint(x), __float_as_uint(x), false, false);
    return hi ? __uint_as_float(r.x) : __uint_as_float(r.y);
#else
    return __shfl_xor(x, 32);
#endif
}

template <int CTRL>
__device__ __forceinline__ float qperm(float x) {
    return __int_as_float(__builtin_amdgcn_update_dpp(0, __float_as_int(x), CTRL, 0xf, 0xf, true));
}
#define QP_X1 0xB1  // quad_perm(1,0,3,2)
#define QP_X2 0x4E  // quad_perm(2,3,0,1)
#define QP_X3 0x1B  // quad_perm(3,2,1,0)

// pre-activation arrives pre-scaled by log2e (tanh rows by 2*log2e):
// sigmoid(a) = 1/(1+2^-ahat); tanh(a) = 2/(1+2^-ahat) - 1
__device__ __forceinline__ float gact2(float ahat, bool is_t) {
    float e  = exp2_fast(-ahat);
    float sg = __fdividef(1.0f, 1.0f + e);
    return is_t ? fmaf(2.0f, sg, -1.0f) : sg;
}
__device__ __forceinline__ float tanh2(float c) {
    float e = exp2_fast(c * (-2.0f * LOG2E));
    return fmaf(2.0f, __fdividef(1.0f, 1.0f + e), -1.0f);
}

// 4 dot2 of one h8v against 4 consecutive h2v weights, alternating accums
#define DOT8(W, WO, H) \
    a0 = fdot2(W[(WO) + 0], S2C(H, 0), a0); \
    a1 = fdot2(W[(WO) + 1], S2C(H, 1), a1); \
    a2 = fdot2(W[(WO) + 2], S2C(H, 2), a2); \
    a3 = fdot2(W[(WO) + 3], S2C(H, 3), a3);

__global__ __launch_bounds__(NT) __attribute__((amdgpu_waves_per_eu(3, 3)))
void lstm2_fused(
    const float* __restrict__ x,     // (B,7,2048)
    const float* __restrict__ Wih0,  // (256,7)
    const float* __restrict__ Whh0,  // (256,64)
    const float* __restrict__ bih0, const float* __restrict__ bhh0,
    const float* __restrict__ Wih1,  // (256,64)
    const float* __restrict__ Whh1,  // (256,64)
    const float* __restrict__ bih1, const float* __restrict__ bhh1,
    const float* __restrict__ W1,    // (10,64)
    const float* __restrict__ b1v,   // (10)
    const float* __restrict__ gmma, const float* __restrict__ beta,
    const float* __restrict__ rm,   const float* __restrict__ rv,
    const float* __restrict__ W2,   // (1,10)
    const float* __restrict__ b2,   // (1)
    float* __restrict__ out)         // (B,1)
{
    const int b    = blockIdx.x;
    const int tid  = threadIdx.x;

    __shared__ __align__(16) half_t xTh[TT][8];   // 32 KB, f16 x, [7]=0 pad
    __shared__ __align__(16) half_t h0s[2][HH];   // f16 hidden, double-buffered
    __shared__ __align__(16) half_t h1s[2][HH];
    __shared__ float yv[10];

    // ---- stage x[b] transposed, converted to f16 ----
    {
        const float* xg = x + (size_t)b * (IND * TT);
        for (int i = tid; i < IND * TT; i += NT) {
            int d = i >> 11;
            int t = i & (TT - 1);
            xTh[t][d] = (half_t)xg[i];
        }
        for (int t = tid; t < TT; t += NT) xTh[t][7] = (half_t)0.0f;
        if (tid < HH) {
            h0s[1][tid] = (half_t)0.0f;
            h1s[0][tid] = (half_t)0.0f;
            h1s[1][tid] = (half_t)0.0f;
        }
    }

    __syncthreads();

    if (tid < 256) {
        // ============ LAYER-0 GROUP (4 waves): h0(tick) at tick, full-k ============
        const int s = tid & 3;           // gate 0:i 1:f 2:g 3:o (quad-local)
        const int j = tid >> 2;          // hidden unit 0..63
        const int g = (s << 6) | j;
        const bool  is_t = (s == 2);
        const float sc   = is_t ? (2.0f * LOG2E) : LOG2E;
        const bool  a1b  = (s & 1) != 0;
        const bool  a2b  = (s & 2) != 0;

        h2v wh[32];
        {
            const float* pw = Whh0 + g * HH;
            #pragma unroll
            for (int r = 0; r < 32; ++r)
                wh[r] = h2v{(half_t)(pw[2*r] * sc), (half_t)(pw[2*r+1] * sc)};
        }
        h2v xw[4];
        {
            float t7[8];
            #pragma unroll
            for (int d = 0; d < IND; ++d) t7[d] = Wih0[g * IND + d] * sc;
            t7[7] = 0.0f;
            #pragma unroll
            for (int r = 0; r < 4; ++r)
                xw[r] = h2v{(half_t)t7[2*r], (half_t)t7[2*r+1]};
        }
        const float bg = (bih0[g] + bhh0[g]) * sc;

        float c0 = 0.0f;
        h8v xv = *((const h8v*)&xTh[0][0]);   // one b128 broadcast read

        for (int tick = 0; tick <= TT; ++tick) {
            const int p = tick & 1;
            if (tick < TT) {
                const h8v* hp = (const h8v*)&h0s[p ^ 1][0];
                h8v H0 = hp[0], H1 = hp[1], H2 = hp[2], H3 = hp[3];
                h8v H4 = hp[4], H5 = hp[5], H6 = hp[6], H7 = hp[7];
                float a0 = bg, a1 = 0.f, a2 = 0.f, a3 = 0.f;
                DOT8(xw, 0, xv)          // x contribution (slot 7 is zero)
                DOT8(wh, 0,  H0) DOT8(wh, 4,  H1)
                DOT8(wh, 8,  H2) DOT8(wh, 12, H3)
                DOT8(wh, 16, H4) DOT8(wh, 20, H5)
                DOT8(wh, 24, H6) DOT8(wh, 28, H7)
                float a = (a0 + a1) + (a2 + a3);
                float act = gact2(a, is_t);
                float x1 = qperm<QP_X1>(act);
                float x2 = qperm<QP_X2>(act);
                float x3 = qperm<QP_X3>(act);
                float p02 = act * x2, p13 = x1 * x3;
                float ig = a1b ? p13 : p02;
                float t1 = a2b ? x2 : act, t2 = a2b ? x3 : x1;
                float fv = a1b ? t1 : t2;
                float o1 = a2b ? act : x2, o2 = a2b ? x1 : x3;
                float ov = a1b ? o1 : o2;
                c0 = fmaf(fv, c0, ig);
                float hn = ov * tanh2(c0);
                if (s == 0) h0s[p][j] = (half_t)hn;
                const int tn = (tick + 1) & (TT - 1);
                xv = *((const h8v*)&xTh[tn][0]);
            }
            __syncthreads();
        }
    } else {
        // ====== LAYER-1 GROUP (8 waves): h1(tick-1) at tick, matrix-half split ======
        const int t2   = tid - 256;
        const int lane = t2 & 63;
        const int w    = t2 >> 6;          // 0..7
        const int s    = lane & 3;
        const int u    = (lane >> 2) & 7;
        const int hi   = lane >> 5;        // 0: Wih1@h0, 1: Whh1@h1
        const int j    = (w << 3) | u;     // hidden unit 0..63
        const int g    = (s << 6) | j;
        const bool  is_t = (s == 2);
        const float sc   = is_t ? (2.0f * LOG2E) : LOG2E;
        const bool  a1b  = (s & 1) != 0;
        const bool  a2b  = (s & 2) != 0;
        const bool  pub  = ((lane & 35) == 0);   // s==0 && hi==0

        h2v wt[32];
        {
            const float* pw = (hi ? Whh1 : Wih1) + g * HH;
            #pragma unroll
            for (int r = 0; r < 32; ++r)
                wt[r] = h2v{(half_t)(pw[2*r] * sc), (half_t)(pw[2*r+1] * sc)};
        }
        const float bg = hi ? 0.0f : (bih1[g] + bhh1[g]) * sc;

        float c1 = 0.0f;

        for (int tick = 0; tick <= TT; ++tick) {
            const int p = tick & 1;
            if (tick > 0) {
                // hi=0 reads h0(tick-1); hi=1 reads h1(tick-2)
                const h8v* hp = hi ? (const h8v*)&h1s[p ^ 1][0]
                                   : (const h8v*)&h0s[p ^ 1][0];
                h8v H0 = hp[0], H1 = hp[1], H2 = hp[2], H3 = hp[3];
                h8v H4 = hp[4], H5 = hp[5], H6 = hp[6], H7 = hp[7];
                float a0 = bg, a1 = 0.f, a2 = 0.f, a3 = 0.f;
                DOT8(wt, 0,  H0) DOT8(wt, 4,  H1)
                DOT8(wt, 8,  H2) DOT8(wt, 12, H3)
                DOT8(wt, 16, H4) DOT8(wt, 20, H5)
                DOT8(wt, 24, H6) DOT8(wt, 28, H7)
                float part = (a0 + a1) + (a2 + a3);
                float full = part + partner32(part, hi);
                float act = gact2(full, is_t);
                float x1 = qperm<QP_X1>(act);
                float x2 = qperm<QP_X2>(act);
                float x3 = qperm<QP_X3>(act);
                float p02 = act * x2, p13 = x1 * x3;
                float ig = a1b ? p13 : p02;
                float t1 = a2b ? x2 : act, t2 = a2b ? x3 : x1;
                float fv = a1b ? t1 : t2;
                float o1 = a2b ? act : x2, o2 = a2b ? x1 : x3;
                float ov = a1b ? o1 : o2;
                c1 = fmaf(fv, c1, ig);
                float hn = ov * tanh2(c1);
                if (pub) h1s[p][j] = (half_t)hn;
            }
            __syncthreads();
        }
    }

    // h1(TT-1) was stored at tick TT into h1s[TT&1] = h1s[0]
    if (tid < 10) {
        float y = b1v[tid];
        #pragma unroll
        for (int k = 0; k < HH; ++k) y += W1[tid * HH + k] * (float)h1s[0][k];
        y = (y - rm[tid]) * rsqrtf(rv[tid] + 1e-5f) * gmma[tid] + beta[tid];
        y = fmaxf(y, 0.0f);
        yv[tid] = y * W2[tid];
    }
    __syncthreads();
    if (tid == 0) {
        float sacc = b2[0];
        #pragma unroll
        for (int k = 0; k < 10; ++k) sacc += yv[k];
        out[b] = sacc;
    }
}

extern "C" void kernel_launch(void* const* d_in, const int* in_sizes, int n_in,
                              void* d_out, int out_size, void* d_ws, size_t ws_size,
                              hipStream_t stream) {
    const float* x    = (const float*)d_in[0];
    const float* Wih0 = (const float*)d_in[1];
    const float* Whh0 = (const float*)d_in[2];
    const float* bih0 = (const float*)d_in[3];
    const float* bhh0 = (const float*)d_in[4];
    const float* Wih1 = (const float*)d_in[5];
    const float* Whh1 = (const float*)d_in[6];
    const float* bih1 = (const float*)d_in[7];
    const float* bhh1 = (const float*)d_in[8];
    const float* W1   = (const float*)d_in[9];
    const float* b1   = (const float*)d_in[10];
    const float* gmma = (const float*)d_in[11];
    const float* beta = (const float*)d_in[12];
    const float* rm   = (const float*)d_in[13];
    const float* rv   = (const float*)d_in[14];
    const float* W2   = (const float*)d_in[15];
    const float* b2   = (const float*)d_in[16];

    const int B = in_sizes[0] / (IND * TT);   // 256

    lstm2_fused<<<dim3(B), dim3(NT), 0, stream>>>(
        x, Wih0, Whh0, bih0, bhh0, Wih1, Whh1, bih1, bhh1,
        W1, b1, gmma, beta, rm, rv, W2, b2, (float*)d_out);
}

// Round 14
// 955.908 us; speedup vs baseline: 1.4022x; 1.4022x over previous
//
#include <hip/hip_runtime.h>
#include <math.h>

#define HH  64
#define TT  2048
#define IND 7
#define NT  256          // 4 waves: 2 L0 + 2 L1, one per SIMD

typedef _Float16 half_t;
typedef _Float16 h2v __attribute__((ext_vector_type(2)));
typedef _Float16 h8v __attribute__((ext_vector_type(8)));
typedef unsigned int u2v __attribute__((ext_vector_type(2)));

#define LOG2E 1.44269504088896f

// constant-index h2v slice of an h8v: exact VGPR subregister
#define S2C(V, I) __builtin_shufflevector(V, V, 2*(I), 2*(I)+1)

// f16 dot2 with fp32 accumulate
__device__ __forceinline__ float fdot2(h2v a, h2v b, float c) {
#if __has_builtin(__builtin_amdgcn_fdot2)
    return __builtin_amdgcn_fdot2(a, b, c, false);
#else
    return fmaf((float)a.x, (float)b.x, fmaf((float)a.y, (float)b.y, c));
#endif
}

__device__ __forceinline__ float exp2_fast(float x) {
#if __has_builtin(__builtin_amdgcn_exp2f)
    return __builtin_amdgcn_exp2f(x);
#else
    return exp2f(x);
#endif
}
__device__ __forceinline__ float rcp_fast(float x) {
#if __has_builtin(__builtin_amdgcn_rcpf)
    return __builtin_amdgcn_rcpf(x);
#else
    return __fdividef(1.0f, x);
#endif
}

// value held by the lane^32 partner (VALU pipe, v_permlane32_swap)
__device__ __forceinline__ float partner32(float x, int hi) {
#if __has_builtin(__builtin_amdgcn_permlane32_swap)
    u2v r = __builtin_amdgcn_permlane32_swap(__float_as_uint(x), __float_as_uint(x), false, false);
    return hi ? __uint_as_float(r.x) : __uint_as_float(r.y);
#else
    return __shfl_xor(x, 32);
#endif
}

// sigmoid with pre-scaled (log2e) argument
__device__ __forceinline__ float sig2(float ahat) {
    return rcp_fast(1.0f + exp2_fast(-ahat));
}
__device__ __forceinline__ float tanh2(float c) {
    float e = exp2_fast(c * (-2.0f * LOG2E));
    return fmaf(2.0f, rcp_fast(1.0f + e), -1.0f);
}

// 4 f16-dot2 of weight block (W)[0..3] against the 4 h2v slices of h8v H
#define DOT4(ACC, W, H) \
    ACC = fdot2((W)[0], S2C(H, 0), ACC); \
    ACC = fdot2((W)[1], S2C(H, 1), ACC); \
    ACC = fdot2((W)[2], S2C(H, 2), ACC); \
    ACC = fdot2((W)[3], S2C(H, 3), ACC);

__global__ __launch_bounds__(NT) __attribute__((amdgpu_waves_per_eu(1, 1)))
void lstm2_fused(
    const float* __restrict__ x,     // (B,7,2048)
    const float* __restrict__ Wih0,  // (256,7)
    const float* __restrict__ Whh0,  // (256,64)
    const float* __restrict__ bih0, const float* __restrict__ bhh0,
    const float* __restrict__ Wih1,  // (256,64)
    const float* __restrict__ Whh1,  // (256,64)
    const float* __restrict__ bih1, const float* __restrict__ bhh1,
    const float* __restrict__ W1,    // (10,64)
    const float* __restrict__ b1v,   // (10)
    const float* __restrict__ gmma, const float* __restrict__ beta,
    const float* __restrict__ rm,   const float* __restrict__ rv,
    const float* __restrict__ W2,   // (1,10)
    const float* __restrict__ b2,   // (1)
    float* __restrict__ out)         // (B,1)
{
    const int b    = blockIdx.x;
    const int tid  = threadIdx.x;
    const int wave = tid >> 6;       // 0,1: L0   2,3: L1
    const int lane = tid & 63;

    __shared__ __align__(16) half_t xTh[TT][8];   // 32 KB, f16 x, [7]=0 pad
    __shared__ __align__(16) half_t h0s[2][HH];   // f16 hidden, double-buffered
    __shared__ __align__(16) half_t h1s[2][HH];
    __shared__ float yv[10];

    // ---- stage x[b] transposed, converted to f16 ----
    {
        const float* xg = x + (size_t)b * (IND * TT);
        for (int i = tid; i < IND * TT; i += NT) {
            int d = i >> 11;
            int t = i & (TT - 1);
            xTh[t][d] = (half_t)xg[i];
        }
        for (int t = tid; t < TT; t += NT) xTh[t][7] = (half_t)0.0f;
        if (tid < HH) {
            h0s[1][tid] = (half_t)0.0f;
            h1s[0][tid] = (half_t)0.0f;
            h1s[1][tid] = (half_t)0.0f;
        }
    }

    __syncthreads();

    if (wave < 2) {
        // ========= LAYER-0 (2 waves): lane = (unit j, k-half kh), 4 gates in-lane =========
        const int j  = ((wave & 1) << 5) | (lane & 31);   // hidden unit 0..63
        const int kh = lane >> 5;                          // k-half (lane bit 5)

        h2v wh[4][16];    // Whh0 half-rows, 4 gates
        h2v xw[4][4];     // Wih0 rows (kh=1 lanes only; zeros otherwise)
        float bg[4];
        #pragma unroll
        for (int s = 0; s < 4; ++s) {
            const int g = (s << 6) | j;
            const float sc = (s == 2) ? 2.0f * LOG2E : LOG2E;
            const float* pw = Whh0 + g * HH + 32 * kh;
            #pragma unroll
            for (int r = 0; r < 16; ++r)
                wh[s][r] = h2v{(half_t)(pw[2*r] * sc), (half_t)(pw[2*r+1] * sc)};
            float t8[8];
            #pragma unroll
            for (int d = 0; d < 8; ++d)
                t8[d] = (d < IND && kh) ? Wih0[g * IND + d] * sc : 0.0f;
            #pragma unroll
            for (int r = 0; r < 4; ++r)
                xw[s][r] = h2v{(half_t)t8[2*r], (half_t)t8[2*r+1]};
            bg[s] = (kh == 0) ? (bih0[g] + bhh0[g]) * sc : 0.0f;
        }

        float c0 = 0.0f;

        for (int tick = 0; tick <= TT; ++tick) {
            const int p = tick & 1;
            if (tick < TT) {
                const h8v* hp = (const h8v*)&h0s[p ^ 1][32 * kh];
                h8v H0 = hp[0], H1 = hp[1], H2 = hp[2], H3 = hp[3];
                h8v XV = *((const h8v*)&xTh[tick][0]);     // uniform broadcast
                float fa[4], fb[4];
                #pragma unroll
                for (int s = 0; s < 4; ++s) {
                    float a = bg[s], bb = 0.0f;
                    DOT4(a,  &wh[s][0],  H0)
                    DOT4(a,  &wh[s][4],  H1)
                    DOT4(bb, &wh[s][8],  H2)
                    DOT4(bb, &wh[s][12], H3)
                    DOT4(a,  &xw[s][0],  XV)
                    fa[s] = a; fb[s] = bb;
                }
                float fi, ff, fg, fo;
                { float pr = fa[0] + fb[0]; fi = pr + partner32(pr, kh); }
                { float pr = fa[1] + fb[1]; ff = pr + partner32(pr, kh); }
                { float pr = fa[2] + fb[2]; fg = pr + partner32(pr, kh); }
                { float pr = fa[3] + fb[3]; fo = pr + partner32(pr, kh); }
                float iv = sig2(fi);
                float fv = sig2(ff);
                float gv = fmaf(2.0f, sig2(fg), -1.0f);
                float ov = sig2(fo);
                c0 = fmaf(fv, c0, iv * gv);
                float hn = ov * tanh2(c0);
                if (kh == 0) h0s[p][j] = (half_t)hn;
            }
            __syncthreads();
        }
    } else {
        // ========= LAYER-1 (2 waves): lane = (unit j, matrix-half mh), one tick behind =========
        const int j  = ((wave & 1) << 5) | (lane & 31);   // hidden unit 0..63
        const int mh = lane >> 5;                          // 0: Wih1@h0, 1: Whh1@h1

        h2v wt[4][32];    // full rows of one matrix, 4 gates
        float bg[4];
        const float* WB = mh ? Whh1 : Wih1;
        #pragma unroll
        for (int s = 0; s < 4; ++s) {
            const int g = (s << 6) | j;
            const float sc = (s == 2) ? 2.0f * LOG2E : LOG2E;
            const float* pw = WB + g * HH;
            #pragma unroll
            for (int r = 0; r < 32; ++r)
                wt[s][r] = h2v{(half_t)(pw[2*r] * sc), (half_t)(pw[2*r+1] * sc)};
            bg[s] = (mh == 0) ? (bih1[g] + bhh1[g]) * sc : 0.0f;
        }

        float c1 = 0.0f;

        for (int tick = 0; tick <= TT; ++tick) {
            const int p = tick & 1;
            if (tick > 0) {
                const h8v* hp = mh ? (const h8v*)&h1s[p ^ 1][0]
                                   : (const h8v*)&h0s[p ^ 1][0];
                h8v H0 = hp[0], H1 = hp[1], H2 = hp[2], H3 = hp[3];
                h8v H4 = hp[4], H5 = hp[5], H6 = hp[6], H7 = hp[7];
                float fa[4], fb[4];
                #pragma unroll
                for (int s = 0; s < 4; ++s) {
                    float a = bg[s], bb = 0.0f;
                    DOT4(a,  &wt[s][0],  H0)
                    DOT4(a,  &wt[s][4],  H1)
                    DOT4(a,  &wt[s][8],  H2)
                    DOT4(a,  &wt[s][12], H3)
                    DOT4(bb, &wt[s][16], H4)
                    DOT4(bb, &wt[s][20], H5)
                    DOT4(bb, &wt[s][24], H6)
                    DOT4(bb, &wt[s][28], H7)
                    fa[s] = a; fb[s] = bb;
                }
                float fi, ff, fg, fo;
                { float pr = fa[0] + fb[0]; fi = pr + partner32(pr, mh); }
                { float pr = fa[1] + fb[1]; ff = pr + partner32(pr, mh); }
                { float pr = fa[2] + fb[2]; fg = pr + partner32(pr, mh); }
                { float pr = fa[3] + fb[3]; fo = pr + partner32(pr, mh); }
                float iv = sig2(fi);
                float fv = sig2(ff);
                float gv = fmaf(2.0f, sig2(fg), -1.0f);
                float ov = sig2(fo);
                c1 = fmaf(fv, c1, iv * gv);
                float hn = ov * tanh2(c1);
                if (mh == 0) h1s[p][j] = (half_t)hn;
            }
            __syncthreads();
        }
    }

    // h1(TT-1) was stored at tick TT into h1s[TT&1] = h1s[0]
    if (tid < 10) {
        float y = b1v[tid];
        #pragma unroll
        for (int k = 0; k < HH; ++k) y += W1[tid * HH + k] * (float)h1s[0][k];
        y = (y - rm[tid]) * rsqrtf(rv[tid] + 1e-5f) * gmma[tid] + beta[tid];
        y = fmaxf(y, 0.0f);
        yv[tid] = y * W2[tid];
    }
    __syncthreads();
    if (tid == 0) {
        float sacc = b2[0];
        #pragma unroll
        for (int k = 0; k < 10; ++k) sacc += yv[k];
        out[b] = sacc;
    }
}

extern "C" void kernel_launch(void* const* d_in, const int* in_sizes, int n_in,
                              void* d_out, int out_size, void* d_ws, size_t ws_size,
                              hipStream_t stream) {
    const float* x    = (const float*)d_in[0];
    const float* Wih0 = (const float*)d_in[1];
    const float* Whh0 = (const float*)d_in[2];
    const float* bih0 = (const float*)d_in[3];
    const float* bhh0 = (const float*)d_in[4];
    const float* Wih1 = (const float*)d_in[5];
    const float* Whh1 = (const float*)d_in[6];
    const float* bih1 = (const float*)d_in[7];
    const float* bhh1 = (const float*)d_in[8];
    const float* W1   = (const float*)d_in[9];
    const float* b1   = (const float*)d_in[10];
    const float* gmma = (const float*)d_in[11];
    const float* beta = (const float*)d_in[12];
    const float* rm   = (const float*)d_in[13];
    const float* rv   = (const float*)d_in[14];
    const float* W2   = (const float*)d_in[15];
    const float* b2   = (const float*)d_in[16];

    const int B = in_sizes[0] / (IND * TT);   // 256

    lstm2_fused<<<dim3(B), dim3(NT), 0, stream>>>(
        x, Wih0, Whh0, bih0, bhh0, Wih1, Whh1, bih1, bhh1,
        W1, b1, gmma, beta, rm, rv, W2, b2, (float*)d_out);
}